// Round 1
// baseline (855.491 us; speedup 1.0000x reference)
//
#include <hip/hip_runtime.h>
#include <math.h>

#define A_TOT  36864
#define N_IMG  32
#define M_GT   32
#define TOTAL_K 256
#define MAX_FG_K 128
#define NCHUNK (A_TOT/256)   // 144

// ---------- monotone float<->uint transform for atomic max over floats ----------
__device__ __forceinline__ unsigned enc_f(float f){
    unsigned u = __float_as_uint(f);
    return (u & 0x80000000u) ? ~u : (u | 0x80000000u);
}
__device__ __forceinline__ float dec_f(unsigned k){
    return (k & 0x80000000u) ? __uint_as_float(k & 0x7FFFFFFFu) : __uint_as_float(~k);
}
#define ENC_NEG1 0x407FFFFFu  // enc_f(-1.0f)

__device__ __forceinline__ int bin_of(float r){
    int b = (int)(r * 1024.0f);
    return b > 1023 ? 1023 : (b < 0 ? 0 : b);
}

// ---------- noinline helpers: single emitted copy => bit-identical across kernels ----------
__device__ __attribute__((noinline)) void pred_and_valid(const float* anc, const float* dl,
                                                         float* pb, int* validOut){
#pragma clang fp contract(off)
    float a0=anc[0], a1=anc[1], a2=anc[2], a3=anc[3];
    float w  = a2 - a0 + 1.0f;
    float h  = a3 - a1 + 1.0f;
    float cx = a0 + 0.5f*w;
    float cy = a1 + 0.5f*h;
    float d0=dl[0], d1=dl[1], d2=dl[2], d3=dl[3];
    float pcx = d0*w + cx;
    float pcy = d1*h + cy;
    float pw = (float)exp((double)d2) * w;
    float ph = (float)exp((double)d3) * h;
    float x1 = pcx - 0.5f*pw;
    float y1 = pcy - 0.5f*ph;
    float x2 = pcx + 0.5f*pw;
    float y2 = pcy + 0.5f*ph;
    pb[0]=x1; pb[1]=y1; pb[2]=x2; pb[3]=y2;
    *validOut = (x1 >= 0.0f) && (y1 >= 0.0f) && (x2 < 1024.0f) && (y2 < 1024.0f);
}

__device__ __attribute__((noinline)) void ov_row(const float* pb, int valid,
                                                 const float* gt, float* ov){
#pragma clang fp contract(off)
    float bx1=pb[0], by1=pb[1], bx2=pb[2], by2=pb[3];
    float area_a = (bx2 - bx1 + 1.0f) * (by2 - by1 + 1.0f);
    for(int m=0; m<M_GT; ++m){
        float gx1=gt[m*4+0], gy1=gt[m*4+1], gx2=gt[m*4+2], gy2=gt[m*4+3];
        float area_g = (gx2 - gx1 + 1.0f) * (gy2 - gy1 + 1.0f);
        float iw = fminf(bx2,gx2) - fmaxf(bx1,gx1) + 1.0f; if(iw < 0.0f) iw = 0.0f;
        float ih = fminf(by2,gy2) - fmaxf(by1,gy1) + 1.0f; if(ih < 0.0f) ih = 0.0f;
        float inter = iw * ih;
        float uni = (area_a + area_g) - inter;
        float v = inter / uni;
        ov[m] = valid ? v : -1.0f;
    }
}

__device__ __attribute__((noinline)) void coeff_fn(const float* a, const float* g, float* cf){
#pragma clang fp contract(off)
    float aw = a[2]-a[0]+1.0f, ah = a[3]-a[1]+1.0f;
    float acx = a[0]+0.5f*aw,  acy = a[1]+0.5f*ah;
    float gw = g[2]-g[0]+1.0f, gh = g[3]-g[1]+1.0f;
    float gcx = g[0]+0.5f*gw,  gcy = g[1]+0.5f*gh;
    cf[0] = (gcx - acx) / aw;
    cf[1] = (gcy - acy) / ah;
    cf[2] = (float)log((double)(gw / aw));
    cf[3] = (float)log((double)(gh / ah));
}

// ---------- K0: init per-gt-max and histograms ----------
__global__ void k_init(unsigned* pgm, int* hist){
    int i = blockIdx.x*256 + threadIdx.x;
    if(i < N_IMG*M_GT)  pgm[i]  = ENC_NEG1;
    if(i < N_IMG*2048)  hist[i] = 0;
}

// ---------- K1: per-gt max IoU (atomic max, LDS-staged) ----------
__global__ void k_iou(const float* __restrict__ anchors, const float* __restrict__ gt,
                      const float* __restrict__ dl, unsigned* __restrict__ pgm){
    int blk = blockIdx.x;
    int n = blk / NCHUNK, ch = blk % NCHUNK;
    int a = ch*256 + threadIdx.x;
    __shared__ unsigned spgm[M_GT];
    if(threadIdx.x < M_GT) spgm[threadIdx.x] = ENC_NEG1;
    __syncthreads();
    float pb[4]; int valid;
    pred_and_valid(anchors + (long)a*4, dl + ((long)n*A_TOT + a)*4, pb, &valid);
    float ov[M_GT];
    ov_row(pb, valid, gt + (long)n*M_GT*4, ov);
    for(int m=0; m<M_GT; ++m) atomicMax(&spgm[m], enc_f(ov[m]));
    __syncthreads();
    if(threadIdx.x < M_GT) atomicMax(&pgm[n*M_GT + threadIdx.x], spgm[threadIdx.x]);
}

// ---------- K2: labels (fg/bg), gt argmax, class histograms ----------
__global__ void k_label(const float* __restrict__ anchors, const float* __restrict__ gt,
                        const float* __restrict__ dl, const float* __restrict__ rscore,
                        int* __restrict__ meta, const unsigned* __restrict__ pgm,
                        int* __restrict__ hist){
    int blk = blockIdx.x;
    int n = blk / NCHUNK, ch = blk % NCHUNK;
    int a = ch*256 + threadIdx.x;
    float pb[4]; int valid;
    pred_and_valid(anchors + (long)a*4, dl + ((long)n*A_TOT + a)*4, pb, &valid);
    float ov[M_GT];
    ov_row(pb, valid, gt + (long)n*M_GT*4, ov);
    float best = ov[0]; int bid = 0;
    for(int m=1; m<M_GT; ++m){ if(ov[m] > best){ best = ov[m]; bid = m; } }
    bool abox = false;
    if(valid){
        for(int m=0; m<M_GT; ++m){
            if(ov[m] == dec_f(pgm[n*M_GT + m])) abox = true;
        }
    }
    bool fg = abox || (best >= 0.7f);          // b_box: amax of where'd row (-1 if invalid)
    bool bg = valid && (best < 0.3f) && !fg;   // labels==0
    long ia = (long)n*A_TOT + a;
    meta[ia] = bid | (fg ? 32 : 0) | (bg ? 64 : 0);
    if(fg || bg){
        int b = bin_of(rscore[ia]);
        atomicAdd(&hist[((long)n*2 + (fg ? 0 : 1))*1024 + b], 1);
    }
}

// ---------- K3: rank-based subsample (top-quota by r desc, idx asc) ----------
__global__ void k_select(const float* __restrict__ rscore, int* __restrict__ meta,
                         const int* __restrict__ hist){
    int n = blockIdx.x, tid = threadIdx.x;
    __shared__ int   sh_hist[1024];
    __shared__ int   sh_scan[256];
    __shared__ float sl_r[2048];
    __shared__ int   sl_a[2048];
    __shared__ int   sh_cnt, sh_b, sh_take, sh_keepAll, sh_K;
    for(int phase=0; phase<2; ++phase){
        __syncthreads();
        int quota = (phase==0) ? MAX_FG_K : (TOTAL_K - sh_K);
        for(int i=tid; i<1024; i+=256) sh_hist[i] = hist[(n*2 + phase)*1024 + i];
        __syncthreads();
        // suffix counts in descending-bin group order
        int b0 = 1023 - 4*tid;
        int part = sh_hist[b0] + sh_hist[b0-1] + sh_hist[b0-2] + sh_hist[b0-3];
        sh_scan[tid] = part;
        __syncthreads();
        for(int off=1; off<256; off<<=1){
            int add = (tid >= off) ? sh_scan[tid-off] : 0;
            __syncthreads();
            sh_scan[tid] += add;
            __syncthreads();
        }
        int pre   = sh_scan[tid] - part;   // count in bins strictly above my group
        int total = sh_scan[255];
        if(tid==0){
            sh_keepAll = (total <= quota) ? 1 : 0;
            sh_b = -1; sh_take = 0; sh_cnt = 0;
            if(phase==0) sh_K = (total < MAX_FG_K) ? total : MAX_FG_K;
        }
        __syncthreads();
        if(!sh_keepAll){
            int cum = pre;
            for(int j=0; j<4; ++j){
                int bb = b0 - j;
                int hh = sh_hist[bb];
                if(cum < quota && cum + hh >= quota){ sh_b = bb; sh_take = quota - cum; }
                cum += hh;
            }
        }
        __syncthreads();
        int classbit = (phase==0) ? 32 : 64;
        int keepbit  = (phase==0) ? 128 : 256;
        int keepAll = sh_keepAll, bsel = sh_b;
        for(int it=0; it<NCHUNK; ++it){
            int a = it*256 + tid;
            long ia = (long)n*A_TOT + a;
            int mv = meta[ia];
            if(mv & classbit){
                if(keepAll){ meta[ia] = mv | keepbit; }
                else{
                    float r = rscore[ia];
                    int b = bin_of(r);
                    if(b > bsel){ meta[ia] = mv | keepbit; }
                    else if(b == bsel){
                        int p = atomicAdd(&sh_cnt, 1);
                        if(p < 2048){ sl_r[p] = r; sl_a[p] = a; }
                    }
                }
            }
        }
        __syncthreads();
        int c = sh_cnt; if(c > 2048) c = 2048;
        int take = sh_take;
        for(int i=tid; i<c; i+=256){
            float ri = sl_r[i]; int ai = sl_a[i]; int rank = 0;
            for(int j=0; j<c; ++j){
                float rj = sl_r[j];
                if(rj > ri || (rj == ri && sl_a[j] < ai)) rank++;
            }
            if(rank < take) meta[(long)n*A_TOT + ai] |= keepbit;
        }
    }
}

// ---------- K4: compact ascending indices, defaults, emit outputs ----------
__global__ void k_out(const float* __restrict__ anchors, const float* __restrict__ gt,
                      const int* __restrict__ meta, float* __restrict__ out){
    int n = blockIdx.x, tid = threadIdx.x;
    float* out_idx = out;
    float* out_fg  = out + (long)N_IMG*TOTAL_K;
    float* out_cf  = out + (long)2*N_IMG*TOTAL_K;
    // defaults: slot padded with anchor 0 (matches zero-init scatter in reference)
    int m0 = meta[(long)n*A_TOT];
    int gid0 = m0 & 31;
    float cf0[4];
    coeff_fn(anchors, gt + ((long)n*M_GT + gid0)*4, cf0);
    out_idx[n*TOTAL_K + tid] = 0.0f;
    out_fg [n*TOTAL_K + tid] = (m0 & 128) ? 1.0f : 0.0f;
    for(int k=0;k<4;++k) out_cf[((long)n*TOTAL_K + tid)*4 + k] = cf0[k];
    __shared__ int s_wsum[4];
    __shared__ int s_run;
    if(tid==0) s_run = 0;
    __syncthreads();
    int wave = tid >> 6, lane = tid & 63;
    for(int it=0; it<NCHUNK; ++it){
        int a = it*256 + tid;
        int mv = meta[(long)n*A_TOT + a];
        int kept = (mv & (128|256)) ? 1 : 0;
        unsigned long long mask = __ballot(kept);
        if(lane==0) s_wsum[wave] = __popcll(mask);
        __syncthreads();
        if(kept){
            int base = s_run;
            for(int w=0; w<wave; ++w) base += s_wsum[w];
            int slot = base + __popcll(mask & ((1ull<<lane)-1ull));
            if(slot < TOTAL_K){
                out_idx[n*TOTAL_K + slot] = (float)a;
                out_fg [n*TOTAL_K + slot] = (mv & 128) ? 1.0f : 0.0f;
                int gid = mv & 31;
                float cf[4];
                coeff_fn(anchors + (long)a*4, gt + ((long)n*M_GT + gid)*4, cf);
                for(int k=0;k<4;++k) out_cf[((long)n*TOTAL_K + slot)*4 + k] = cf[k];
            }
        }
        __syncthreads();
        if(tid==0) s_run += s_wsum[0]+s_wsum[1]+s_wsum[2]+s_wsum[3];
        __syncthreads();
    }
}

extern "C" void kernel_launch(void* const* d_in, const int* in_sizes, int n_in,
                              void* d_out, int out_size, void* d_ws, size_t ws_size,
                              hipStream_t stream){
    const float* anchors = (const float*)d_in[0];  // [36864,4]
    const float* gt      = (const float*)d_in[1];  // [32,32,4]
    const float* dl      = (const float*)d_in[2];  // [32,36864,4]
    const float* rs      = (const float*)d_in[3];  // [32,36864]
    float* out = (float*)d_out;                    // idx[32,256] | fg[32,256] | coeff[32,256,4]
    char* ws = (char*)d_ws;
    int*      meta = (int*)ws;                                       // N*A ints
    unsigned* pgm  = (unsigned*)(ws + (size_t)N_IMG*A_TOT*4);        // N*M
    int*      hist = (int*)(ws + (size_t)N_IMG*A_TOT*4 + 4096);      // N*2*1024

    hipLaunchKernelGGL(k_init,   dim3(256),            dim3(256), 0, stream, pgm, hist);
    hipLaunchKernelGGL(k_iou,    dim3(N_IMG*NCHUNK),   dim3(256), 0, stream, anchors, gt, dl, pgm);
    hipLaunchKernelGGL(k_label,  dim3(N_IMG*NCHUNK),   dim3(256), 0, stream, anchors, gt, dl, rs, meta, pgm, hist);
    hipLaunchKernelGGL(k_select, dim3(N_IMG),          dim3(256), 0, stream, rs, meta, hist);
    hipLaunchKernelGGL(k_out,    dim3(N_IMG),          dim3(256), 0, stream, anchors, gt, meta, out);
}

// Round 2
// 305.086 us; speedup vs baseline: 2.8041x; 2.8041x over previous
//
#include <hip/hip_runtime.h>
#include <math.h>

#define A_TOT  36864
#define N_IMG  32
#define M_GT   32
#define TOTAL_K 256
#define MAX_FG_K 128
#define NCHUNK 144          // A_TOT / 256
#define KEEPB  (1<<17)
#define CAP    1024

// ---------- monotone float<->uint transform for atomic max over floats ----------
__device__ __forceinline__ unsigned enc_f(float f){
    unsigned u = __float_as_uint(f);
    return (u & 0x80000000u) ? ~u : (u | 0x80000000u);
}
__device__ __forceinline__ float dec_f(unsigned k){
    return (k & 0x80000000u) ? __uint_as_float(k & 0x7FFFFFFFu) : __uint_as_float(~k);
}
#define ENC_NEG1 0x407FFFFFu  // enc_f(-1.0f)

__device__ __forceinline__ int bin_of(float r){
    int b = (int)(r * 1024.0f);
    return b > 1023 ? 1023 : (b < 0 ? 0 : b);
}

// ---------- inline helpers; contract(off) => pure IEEE fp32, bit-identical in
// ---------- every kernel they are inlined into (no fma fusion / reassociation)
struct Pred { float x1,y1,x2,y2,area; int valid; };

__device__ __forceinline__ Pred mk_pred(float4 a, float4 d){
#pragma clang fp contract(off)
    Pred p;
    float w  = a.z - a.x + 1.0f;
    float h  = a.w - a.y + 1.0f;
    float cx = a.x + 0.5f*w;
    float cy = a.y + 0.5f*h;
    float pcx = d.x*w + cx;
    float pcy = d.y*h + cy;
    float pw = (float)exp((double)d.z) * w;
    float ph = (float)exp((double)d.w) * h;
    p.x1 = pcx - 0.5f*pw;
    p.y1 = pcy - 0.5f*ph;
    p.x2 = pcx + 0.5f*pw;
    p.y2 = pcy + 0.5f*ph;
    p.valid = (p.x1 >= 0.0f) && (p.y1 >= 0.0f) && (p.x2 < 1024.0f) && (p.y2 < 1024.0f);
    p.area  = (p.x2 - p.x1 + 1.0f) * (p.y2 - p.y1 + 1.0f);
    return p;
}

__device__ __forceinline__ float gt_area(float4 g){
#pragma clang fp contract(off)
    return (g.z - g.x + 1.0f) * (g.w - g.y + 1.0f);
}

__device__ __forceinline__ float iou_val(const Pred& p, float gx1, float gy1,
                                         float gx2, float gy2, float ga){
#pragma clang fp contract(off)
    float iw = fminf(p.x2,gx2) - fmaxf(p.x1,gx1) + 1.0f; iw = iw < 0.0f ? 0.0f : iw;
    float ih = fminf(p.y2,gy2) - fmaxf(p.y1,gy1) + 1.0f; ih = ih < 0.0f ? 0.0f : ih;
    float inter = iw * ih;
    float uni = (p.area + ga) - inter;
    float v = inter / uni;
    return p.valid ? v : -1.0f;
}

__device__ __forceinline__ void coeff_fn(float4 a, float4 g, float cf[4]){
#pragma clang fp contract(off)
    float aw = a.z - a.x + 1.0f, ah = a.w - a.y + 1.0f;
    float acx = a.x + 0.5f*aw,  acy = a.y + 0.5f*ah;
    float gw = g.z - g.x + 1.0f, gh = g.w - g.y + 1.0f;
    float gcx = g.x + 0.5f*gw,  gcy = g.y + 0.5f*gh;
    cf[0] = (gcx - acx) / aw;
    cf[1] = (gcy - acy) / ah;
    cf[2] = (float)log((double)(gw / aw));
    cf[3] = (float)log((double)(gh / ah));
}

// ---------- K0: init per-gt-max and histograms ----------
__global__ void k_init(unsigned* pgm, int* hist){
    int i = blockIdx.x*256 + threadIdx.x;
    if(i < N_IMG*M_GT)  pgm[i]  = ENC_NEG1;
    if(i < N_IMG*2048)  hist[i] = 0;
}

// ---------- K1: per-gt max IoU (register-resident, staggered LDS atomics) ----------
__global__ void k_iou(const float* __restrict__ anchors, const float* __restrict__ gt,
                      const float* __restrict__ dl, unsigned* __restrict__ pgm){
    int blk = blockIdx.x;
    int n = blk / NCHUNK, ch = blk % NCHUNK;
    int tid = threadIdx.x;
    int a = ch*256 + tid;
    __shared__ float sgx1[M_GT], sgy1[M_GT], sgx2[M_GT], sgy2[M_GT], sga[M_GT];
    __shared__ unsigned spgm[M_GT];
    if(tid < M_GT){
        float4 g = ((const float4*)gt)[n*M_GT + tid];
        sgx1[tid]=g.x; sgy1[tid]=g.y; sgx2[tid]=g.z; sgy2[tid]=g.w;
        sga[tid]=gt_area(g);
        spgm[tid]=ENC_NEG1;
    }
    __syncthreads();
    float4 anc = ((const float4*)anchors)[a];
    float4 d   = ((const float4*)dl)[(long)n*A_TOT + a];
    Pred p = mk_pred(anc, d);
    #pragma unroll 8
    for(int j=0;j<M_GT;++j){
        int m = (tid + j) & 31;               // stagger: spread banks/addresses
        float v = iou_val(p, sgx1[m], sgy1[m], sgx2[m], sgy2[m], sga[m]);
        atomicMax(&spgm[m], enc_f(v));
    }
    __syncthreads();
    if(tid < M_GT) atomicMax(&pgm[n*M_GT + tid], spgm[tid]);
}

// ---------- K2: labels (fg/bg), gt argmax, bin into meta, class histograms ----------
__global__ void k_label(const float* __restrict__ anchors, const float* __restrict__ gt,
                        const float* __restrict__ dl, const float* __restrict__ rscore,
                        int* __restrict__ meta, const unsigned* __restrict__ pgm,
                        int* __restrict__ hist){
    int blk = blockIdx.x;
    int n = blk / NCHUNK, ch = blk % NCHUNK;
    int tid = threadIdx.x;
    int a = ch*256 + tid;
    __shared__ float sgx1[M_GT], sgy1[M_GT], sgx2[M_GT], sgy2[M_GT], sga[M_GT];
    __shared__ float spgm[M_GT];
    if(tid < M_GT){
        float4 g = ((const float4*)gt)[n*M_GT + tid];
        sgx1[tid]=g.x; sgy1[tid]=g.y; sgx2[tid]=g.z; sgy2[tid]=g.w;
        sga[tid]=gt_area(g);
        spgm[tid]=dec_f(pgm[n*M_GT + tid]);
    }
    __syncthreads();
    float4 anc = ((const float4*)anchors)[a];
    float4 d   = ((const float4*)dl)[(long)n*A_TOT + a];
    Pred p = mk_pred(anc, d);
    float best = -INFINITY; int bid = 0; bool abox = false;
    for(int m=0;m<M_GT;++m){                  // ascending m: first-argmax semantics
        float v = iou_val(p, sgx1[m], sgy1[m], sgx2[m], sgy2[m], sga[m]);
        if(v > best){ best = v; bid = m; }
        if(p.valid && v == spgm[m]) abox = true;
    }
    bool fg = abox || (best >= 0.7f);
    bool bg = p.valid && (best < 0.3f) && !fg;
    long ia = (long)n*A_TOT + a;
    int bin = bin_of(rscore[ia]);
    meta[ia] = bid | (fg?32:0) | (bg?64:0) | (bin<<7);
    if(fg || bg) atomicAdd(&hist[(n*2 + (fg?0:1))*1024 + bin], 1);
}

// ---------- K3: quotas from histograms + single meta pass + boundary ranking ----------
__global__ void k_select(const float* __restrict__ rscore, int* __restrict__ meta,
                         const int* __restrict__ hist){
    int n = blockIdx.x, tid = threadIdx.x;
    __shared__ int sh_hist[2048];
    __shared__ int sscan[256];
    __shared__ int q_bsel[2], q_take[2], s_cnt[2];
    __shared__ int sh_fgK;
    __shared__ float bl_r[2][CAP];
    __shared__ int   bl_a[2][CAP];
    for(int i=tid;i<2048;i+=256) sh_hist[i] = hist[n*2048 + i];
    __syncthreads();
    for(int phase=0; phase<2; ++phase){
        int base = phase*1024;
        int b0 = 1023 - 4*tid;                 // this thread's group: bins b0..b0-3 (desc)
        int4 h4 = *(const int4*)&sh_hist[base + b0 - 3];   // {b0-3,b0-2,b0-1,b0}
        int part = h4.x + h4.y + h4.z + h4.w;
        sscan[tid] = part;
        __syncthreads();
        for(int off=1; off<256; off<<=1){
            int add = (tid>=off) ? sscan[tid-off] : 0;
            __syncthreads();
            sscan[tid] += add;
            __syncthreads();
        }
        int total = sscan[255];
        if(tid==0){
            q_bsel[phase] = -1; q_take[phase] = 0; s_cnt[phase] = 0;
            if(phase==0) sh_fgK = (total < MAX_FG_K) ? total : MAX_FG_K;
        }
        __syncthreads();
        int quota = (phase==0) ? MAX_FG_K : (TOTAL_K - sh_fgK);
        if(total > quota){
            int pre = sscan[tid] - part;       // count in bins strictly above my group
            int cum = pre;
            int hs[4] = {h4.w, h4.z, h4.y, h4.x};   // descending bin order
            for(int j=0;j<4;++j){
                int hh = hs[j];
                if(cum < quota && cum + hh >= quota){ q_bsel[phase] = b0 - j; q_take[phase] = quota - cum; }
                cum += hh;
            }
        }
        __syncthreads();
    }
    int bs0 = q_bsel[0], bs1 = q_bsel[1];
    // one pass over meta: mark sure-keeps, collect boundary-bin candidates
    for(int it=0; it<NCHUNK; ++it){
        int a = it*256 + tid;
        long ia = (long)n*A_TOT + a;
        int mv = meta[ia];
        int cls = (mv >> 5) & 3;               // 1=fg, 2=bg
        if(cls){
            int c = (cls==1) ? 0 : 1;
            int bsel = c ? bs1 : bs0;
            int bin = (mv >> 7) & 1023;
            if(bin > bsel) meta[ia] = mv | KEEPB;
            else if(bin == bsel){
                int pos = atomicAdd(&s_cnt[c], 1);
                if(pos < CAP){ bl_r[c][pos] = rscore[ia]; bl_a[c][pos] = a; }
            }
        }
    }
    __syncthreads();
    // exact rank inside the boundary bin: (r desc, index asc)
    for(int c=0;c<2;++c){
        int cc = s_cnt[c]; if(cc > CAP) cc = CAP;
        int take = q_take[c];
        for(int i=tid; i<cc; i+=256){
            float ri = bl_r[c][i]; int ai = bl_a[c][i]; int rank = 0;
            for(int j=0;j<cc;++j){
                float rj = bl_r[c][j];
                if(rj > ri || (rj == ri && bl_a[c][j] < ai)) rank++;
            }
            if(rank < take) meta[(long)n*A_TOT + ai] |= KEEPB;
        }
    }
}

// ---------- K4: two-pass ballot compaction (2 barriers), emit outputs ----------
__global__ void k_out(const float* __restrict__ anchors, const float* __restrict__ gt,
                      const int* __restrict__ meta, float* __restrict__ out){
    int n = blockIdx.x, tid = threadIdx.x;
    int wave = tid >> 6, lane = tid & 63;
    __shared__ int scnt[NCHUNK*4];
    __shared__ int sscan[256];
    __shared__ int cbase[NCHUNK];
    float* out_idx = out;
    float* out_fg  = out + (long)N_IMG*TOTAL_K;
    float* out_cf  = out + (long)2*N_IMG*TOTAL_K;
    // defaults: padding slots behave like anchor 0 (reference zero-init scatter)
    int m0 = meta[(long)n*A_TOT];
    {
        float4 a0 = ((const float4*)anchors)[0];
        float4 g0 = ((const float4*)gt)[n*M_GT + (m0 & 31)];
        float cf0[4]; coeff_fn(a0, g0, cf0);
        out_idx[n*TOTAL_K + tid] = 0.0f;
        out_fg [n*TOTAL_K + tid] = (((m0>>17)&1) && ((m0>>5)&1)) ? 1.0f : 0.0f;
        for(int k=0;k<4;++k) out_cf[((long)n*TOTAL_K + tid)*4 + k] = cf0[k];
    }
    // pass A: per-chunk per-wave kept counts
    for(int it=0; it<NCHUNK; ++it){
        int mv = meta[(long)n*A_TOT + it*256 + tid];
        unsigned long long mask = __ballot((mv >> 17) & 1);
        if(lane==0) scnt[it*4 + wave] = __popcll(mask);
    }
    __syncthreads();
    int v = (tid < NCHUNK) ? (scnt[tid*4] + scnt[tid*4+1] + scnt[tid*4+2] + scnt[tid*4+3]) : 0;
    sscan[tid] = v;
    __syncthreads();
    for(int off=1; off<256; off<<=1){
        int add = (tid>=off) ? sscan[tid-off] : 0;
        __syncthreads();
        sscan[tid] += add;
        __syncthreads();
    }
    if(tid < NCHUNK) cbase[tid] = sscan[tid] - v;   // exclusive chunk base
    __syncthreads();
    // pass B: emit
    for(int it=0; it<NCHUNK; ++it){
        int a = it*256 + tid;
        int mv = meta[(long)n*A_TOT + a];
        int kept = (mv >> 17) & 1;
        unsigned long long mask = __ballot(kept);
        if(kept){
            int base = cbase[it];
            for(int w=0; w<wave; ++w) base += scnt[it*4 + w];
            int slot = base + __popcll(mask & ((1ull<<lane)-1ull));
            if(slot < TOTAL_K){
                out_idx[n*TOTAL_K + slot] = (float)a;
                out_fg [n*TOTAL_K + slot] = ((mv>>5)&1) ? 1.0f : 0.0f;
                float4 aa = ((const float4*)anchors)[a];
                float4 gg = ((const float4*)gt)[n*M_GT + (mv & 31)];
                float cf[4]; coeff_fn(aa, gg, cf);
                for(int k=0;k<4;++k) out_cf[((long)n*TOTAL_K + slot)*4 + k] = cf[k];
            }
        }
    }
}

extern "C" void kernel_launch(void* const* d_in, const int* in_sizes, int n_in,
                              void* d_out, int out_size, void* d_ws, size_t ws_size,
                              hipStream_t stream){
    const float* anchors = (const float*)d_in[0];  // [36864,4]
    const float* gt      = (const float*)d_in[1];  // [32,32,4]
    const float* dl      = (const float*)d_in[2];  // [32,36864,4]
    const float* rs      = (const float*)d_in[3];  // [32,36864]
    float* out = (float*)d_out;                    // idx[32,256] | fg[32,256] | coeff[32,256,4]
    char* ws = (char*)d_ws;
    int*      meta = (int*)ws;                                       // N*A ints
    unsigned* pgm  = (unsigned*)(ws + (size_t)N_IMG*A_TOT*4);        // N*M
    int*      hist = (int*)(ws + (size_t)N_IMG*A_TOT*4 + 4096);     // N*2*1024

    hipLaunchKernelGGL(k_init,   dim3(256),          dim3(256), 0, stream, pgm, hist);
    hipLaunchKernelGGL(k_iou,    dim3(N_IMG*NCHUNK), dim3(256), 0, stream, anchors, gt, dl, pgm);
    hipLaunchKernelGGL(k_label,  dim3(N_IMG*NCHUNK), dim3(256), 0, stream, anchors, gt, dl, rs, meta, pgm, hist);
    hipLaunchKernelGGL(k_select, dim3(N_IMG),        dim3(256), 0, stream, rs, meta, hist);
    hipLaunchKernelGGL(k_out,    dim3(N_IMG),        dim3(256), 0, stream, anchors, gt, meta, out);
}

// Round 3
// 171.943 us; speedup vs baseline: 4.9754x; 1.7743x over previous
//
#include <hip/hip_runtime.h>
#include <math.h>

#define A_TOT  36864
#define N_IMG  32
#define M_GT   32
#define TOTAL_K 256
#define MAX_FG_K 128
#define NCHUNK 144          // A_TOT / 256
#define KEEPB  (1<<17)
#define CAP    512

// ---------- monotone float<->uint transform for atomic max over floats ----------
// enc2 is shifted so enc2(-1.0f) == 0  => init by zeroing
__device__ __forceinline__ unsigned enc2(float f){
    unsigned u = __float_as_uint(f);
    unsigned e = (u & 0x80000000u) ? ~u : (u | 0x80000000u);
    return e - 0x407FFFFFu;
}
__device__ __forceinline__ float dec2(unsigned k){
    unsigned e = k + 0x407FFFFFu;
    return (e & 0x80000000u) ? __uint_as_float(e & 0x7FFFFFFFu) : __uint_as_float(~e);
}

__device__ __forceinline__ int bin_of(float r){
    int b = (int)(r * 1024.0f);
    return b > 1023 ? 1023 : (b < 0 ? 0 : b);
}

// ---------- inline helpers; contract(off) => pure IEEE fp32, bit-identical in
// ---------- every kernel they are inlined into (no fma fusion / reassociation)
struct Pred { float x1,y1,x2,y2,area; int valid; };

__device__ __forceinline__ Pred mk_pred(float4 a, float4 d){
#pragma clang fp contract(off)
    Pred p;
    float w  = a.z - a.x + 1.0f;
    float h  = a.w - a.y + 1.0f;
    float cx = a.x + 0.5f*w;
    float cy = a.y + 0.5f*h;
    float pcx = d.x*w + cx;
    float pcy = d.y*h + cy;
    float pw = (float)exp((double)d.z) * w;
    float ph = (float)exp((double)d.w) * h;
    p.x1 = pcx - 0.5f*pw;
    p.y1 = pcy - 0.5f*ph;
    p.x2 = pcx + 0.5f*pw;
    p.y2 = pcy + 0.5f*ph;
    p.valid = (p.x1 >= 0.0f) && (p.y1 >= 0.0f) && (p.x2 < 1024.0f) && (p.y2 < 1024.0f);
    p.area  = (p.x2 - p.x1 + 1.0f) * (p.y2 - p.y1 + 1.0f);
    return p;
}

__device__ __forceinline__ float gt_area(float4 g){
#pragma clang fp contract(off)
    return (g.z - g.x + 1.0f) * (g.w - g.y + 1.0f);
}

__device__ __forceinline__ float iou_val(const Pred& p, float gx1, float gy1,
                                         float gx2, float gy2, float ga){
#pragma clang fp contract(off)
    float iw = fminf(p.x2,gx2) - fmaxf(p.x1,gx1) + 1.0f; iw = iw < 0.0f ? 0.0f : iw;
    float ih = fminf(p.y2,gy2) - fmaxf(p.y1,gy1) + 1.0f; ih = ih < 0.0f ? 0.0f : ih;
    float inter = iw * ih;
    float uni = (p.area + ga) - inter;
    float v = inter / uni;
    return p.valid ? v : -1.0f;
}

__device__ __forceinline__ void coeff_fn(float4 a, float4 g, float cf[4]){
#pragma clang fp contract(off)
    float aw = a.z - a.x + 1.0f, ah = a.w - a.y + 1.0f;
    float acx = a.x + 0.5f*aw,  acy = a.y + 0.5f*ah;
    float gw = g.z - g.x + 1.0f, gh = g.w - g.y + 1.0f;
    float gcx = g.x + 0.5f*gw,  gcy = g.y + 0.5f*gh;
    cf[0] = (gcx - acx) / aw;
    cf[1] = (gcy - acy) / ah;
    cf[2] = (float)log((double)(gw / aw));
    cf[3] = (float)log((double)(gh / ah));
}

// ---------- K0: zero [pgm | hist | candcnt] (contiguous, 66624 ints) ----------
__global__ void k_init(int* base){
    int i = blockIdx.x*256 + threadIdx.x;
    if(i < 66624) base[i] = 0;
}

// ---------- K1: per-gt max IoU (register-resident, staggered LDS atomics) ----------
__global__ void k_iou(const float* __restrict__ anchors, const float* __restrict__ gt,
                      const float* __restrict__ dl, unsigned* __restrict__ pgm){
    int blk = blockIdx.x;
    int n = blk / NCHUNK, ch = blk % NCHUNK;
    int tid = threadIdx.x;
    int a = ch*256 + tid;
    __shared__ float sgx1[M_GT], sgy1[M_GT], sgx2[M_GT], sgy2[M_GT], sga[M_GT];
    __shared__ unsigned spgm[M_GT];
    if(tid < M_GT){
        float4 g = ((const float4*)gt)[n*M_GT + tid];
        sgx1[tid]=g.x; sgy1[tid]=g.y; sgx2[tid]=g.z; sgy2[tid]=g.w;
        sga[tid]=gt_area(g);
        spgm[tid]=0u;               // enc2(-1.0f)
    }
    __syncthreads();
    float4 anc = ((const float4*)anchors)[a];
    float4 d   = ((const float4*)dl)[(long)n*A_TOT + a];
    Pred p = mk_pred(anc, d);
    #pragma unroll 8
    for(int j=0;j<M_GT;++j){
        int m = (tid + j) & 31;
        float v = iou_val(p, sgx1[m], sgy1[m], sgx2[m], sgy2[m], sga[m]);
        atomicMax(&spgm[m], enc2(v));
    }
    __syncthreads();
    if(tid < M_GT) atomicMax(&pgm[n*M_GT + tid], spgm[tid]);
}

// ---------- K2: labels (fg/bg), gt argmax, bin into meta, class histograms ----------
__global__ void k_label(const float* __restrict__ anchors, const float* __restrict__ gt,
                        const float* __restrict__ dl, const float* __restrict__ rscore,
                        int* __restrict__ meta, const unsigned* __restrict__ pgm,
                        int* __restrict__ hist){
    int blk = blockIdx.x;
    int n = blk / NCHUNK, ch = blk % NCHUNK;
    int tid = threadIdx.x;
    int a = ch*256 + tid;
    __shared__ float sgx1[M_GT], sgy1[M_GT], sgx2[M_GT], sgy2[M_GT], sga[M_GT];
    __shared__ float spgm[M_GT];
    if(tid < M_GT){
        float4 g = ((const float4*)gt)[n*M_GT + tid];
        sgx1[tid]=g.x; sgy1[tid]=g.y; sgx2[tid]=g.z; sgy2[tid]=g.w;
        sga[tid]=gt_area(g);
        spgm[tid]=dec2(pgm[n*M_GT + tid]);
    }
    __syncthreads();
    float4 anc = ((const float4*)anchors)[a];
    float4 d   = ((const float4*)dl)[(long)n*A_TOT + a];
    Pred p = mk_pred(anc, d);
    float best = -INFINITY; int bid = 0; bool abox = false;
    for(int m=0;m<M_GT;++m){                  // ascending m: first-argmax semantics
        float v = iou_val(p, sgx1[m], sgy1[m], sgx2[m], sgy2[m], sga[m]);
        if(v > best){ best = v; bid = m; }
        if(p.valid && v == spgm[m]) abox = true;
    }
    bool fg = abox || (best >= 0.7f);
    bool bg = p.valid && (best < 0.3f) && !fg;
    long ia = (long)n*A_TOT + a;
    int bin = bin_of(rscore[ia]);
    meta[ia] = bid | (fg?32:0) | (bg?64:0) | (bin<<7);
    if(fg || bg) atomicAdd(&hist[(n*2 + (fg?0:1))*1024 + bin], 1);
}

// ---------- K3: per-image quotas: boundary bin + take per class ----------
__global__ void k_quota(const int* __restrict__ hist, int* __restrict__ q){
    int n = blockIdx.x, tid = threadIdx.x;
    __shared__ int sh[2048];
    __shared__ int sscan[256];
    __shared__ int s_b[2], s_t[2], s_fgK;
    for(int i=tid;i<2048;i+=256) sh[i] = hist[n*2048 + i];
    __syncthreads();
    for(int phase=0; phase<2; ++phase){
        int b0 = 1023 - 4*tid;                              // group bins b0..b0-3 (desc)
        int4 h4 = *(const int4*)&sh[phase*1024 + b0 - 3];   // {b0-3,b0-2,b0-1,b0}
        int part = h4.x + h4.y + h4.z + h4.w;
        sscan[tid] = part;
        __syncthreads();
        for(int off=1; off<256; off<<=1){
            int add = (tid>=off) ? sscan[tid-off] : 0;
            __syncthreads();
            sscan[tid] += add;
            __syncthreads();
        }
        int total = sscan[255];
        if(tid==0){
            s_b[phase] = -1; s_t[phase] = 0;
            if(phase==0) s_fgK = (total < MAX_FG_K) ? total : MAX_FG_K;
        }
        __syncthreads();
        int quota = (phase==0) ? MAX_FG_K : (TOTAL_K - s_fgK);
        if(total > quota){
            int pre = sscan[tid] - part;       // count in bins strictly above my group
            int cum = pre;
            int hs[4] = {h4.w, h4.z, h4.y, h4.x};   // descending bin order
            for(int j=0;j<4;++j){
                int hh = hs[j];
                if(cum < quota && cum + hh >= quota){ s_b[phase] = b0 - j; s_t[phase] = quota - cum; }
                cum += hh;
            }
        }
        __syncthreads();
    }
    if(tid==0){
        q[n*4+0]=s_b[0]; q[n*4+1]=s_t[0]; q[n*4+2]=s_b[1]; q[n*4+3]=s_t[1];
    }
}

// ---------- K4: chunk-parallel sure-keep counts + boundary candidate collection ----------
__global__ void k_bound(const int* __restrict__ meta, const float* __restrict__ rscore,
                        const int* __restrict__ q, int* __restrict__ chunk_cnt,
                        int* __restrict__ candcnt, float* __restrict__ cand_r,
                        int* __restrict__ cand_a){
    int blk = blockIdx.x;
    int n = blk / NCHUNK, ch = blk % NCHUNK;
    int tid = threadIdx.x;
    int wave = tid >> 6, lane = tid & 63;
    int a = ch*256 + tid;
    int4 qq = *(const int4*)&q[n*4];            // bsel0, take0, bsel1, take1
    long ia = (long)n*A_TOT + a;
    int mv = meta[ia];
    int cls = (mv >> 5) & 3;                    // 1=fg, 2=bg
    int kept = 0;
    if(cls){
        int c = (cls==1) ? 0 : 1;
        int bsel = c ? qq.z : qq.x;
        int bin = (mv >> 7) & 1023;
        if(bin > bsel) kept = 1;                // keepAll encoded as bsel=-1
        else if(bin == bsel){
            int pos = atomicAdd(&candcnt[n*2+c], 1);
            if(pos < CAP){
                int ci = (n*2+c)*CAP + pos;
                cand_r[ci] = rscore[ia];
                cand_a[ci] = a;
            }
        }
    }
    __shared__ int wc[4];
    unsigned long long mask = __ballot(kept);
    if(lane==0) wc[wave] = __popcll(mask);
    __syncthreads();
    if(tid==0) chunk_cnt[n*NCHUNK + ch] = wc[0]+wc[1]+wc[2]+wc[3];
}

// ---------- K5: rank boundary candidates, chunk-base scan, default outputs ----------
__global__ void k_rankscan(const float* __restrict__ anchors, const float* __restrict__ gt,
                           int* __restrict__ meta, const int* __restrict__ q,
                           const int* __restrict__ candcnt,
                           const float* __restrict__ cand_r, const int* __restrict__ cand_a,
                           const int* __restrict__ chunk_cnt, int* __restrict__ cbase,
                           float* __restrict__ out){
    int n = blockIdx.x, tid = threadIdx.x;
    __shared__ int s_chunk[NCHUNK];
    __shared__ int sscan[256];
    __shared__ int s_k0b;                        // anchor0 boundary-kept-as-fg flag
    if(tid < NCHUNK) s_chunk[tid] = chunk_cnt[n*NCHUNK + tid];
    if(tid==0) s_k0b = 0;
    int4 qq = *(const int4*)&q[n*4];
    __syncthreads();
    for(int c=0;c<2;++c){
        int cc = candcnt[n*2+c]; if(cc > CAP) cc = CAP;
        int take = c ? qq.w : qq.y;
        for(int i=tid; i<cc; i+=256){
            int ci = (n*2+c)*CAP + i;
            float ri = cand_r[ci]; int ai = cand_a[ci]; int rank = 0;
            for(int j=0;j<cc;++j){
                float rj = cand_r[(n*2+c)*CAP + j];
                if(rj > ri || (rj == ri && cand_a[(n*2+c)*CAP + j] < ai)) rank++;
            }
            if(rank < take){
                meta[(long)n*A_TOT + ai] |= KEEPB;
                atomicAdd(&s_chunk[ai >> 8], 1);
                if(ai == 0 && c == 0) s_k0b = 1;
            }
        }
    }
    __syncthreads();
    int v = (tid < NCHUNK) ? s_chunk[tid] : 0;
    sscan[tid] = v;
    __syncthreads();
    for(int off=1; off<256; off<<=1){
        int add = (tid>=off) ? sscan[tid-off] : 0;
        __syncthreads();
        sscan[tid] += add;
        __syncthreads();
    }
    if(tid < NCHUNK) cbase[n*NCHUNK + tid] = sscan[tid] - v;
    // defaults: padding slots behave like anchor 0 (reference zero-init scatter).
    // meta low bits unchanged by any KEEPB |= , so this read is race-free for cls/bin/bid.
    int m0 = meta[(long)n*A_TOT];
    int cls0 = (m0 >> 5) & 3, bin0 = (m0 >> 7) & 1023;
    float fgdef = ((cls0 == 1) && (bin0 > qq.x || s_k0b)) ? 1.0f : 0.0f;
    float4 a0 = ((const float4*)anchors)[0];
    float4 g0 = ((const float4*)gt)[n*M_GT + (m0 & 31)];
    float cf0[4]; coeff_fn(a0, g0, cf0);
    float* out_idx = out;
    float* out_fg  = out + (long)N_IMG*TOTAL_K;
    float* out_cf  = out + (long)2*N_IMG*TOTAL_K;
    out_idx[n*TOTAL_K + tid] = 0.0f;
    out_fg [n*TOTAL_K + tid] = fgdef;
    for(int k=0;k<4;++k) out_cf[((long)n*TOTAL_K + tid)*4 + k] = cf0[k];
}

// ---------- K6: chunk-parallel compaction + emit ----------
__global__ void k_out(const float* __restrict__ anchors, const float* __restrict__ gt,
                      const int* __restrict__ meta, const int* __restrict__ q,
                      const int* __restrict__ cbase, float* __restrict__ out){
    int blk = blockIdx.x;
    int n = blk / NCHUNK, ch = blk % NCHUNK;
    int tid = threadIdx.x;
    int wave = tid >> 6, lane = tid & 63;
    int a = ch*256 + tid;
    int4 qq = *(const int4*)&q[n*4];
    int mv = meta[(long)n*A_TOT + a];
    int cls = (mv >> 5) & 3;
    int kept = 0;
    if(cls){
        int c = (cls==1) ? 0 : 1;
        int bsel = c ? qq.z : qq.x;
        int bin = (mv >> 7) & 1023;
        kept = (bin > bsel) || ((mv & KEEPB) != 0);
    }
    __shared__ int wc[4];
    unsigned long long mask = __ballot(kept);
    if(lane==0) wc[wave] = __popcll(mask);
    __syncthreads();
    if(kept){
        int base = cbase[n*NCHUNK + ch];
        for(int w=0; w<wave; ++w) base += wc[w];
        int slot = base + __popcll(mask & ((1ull<<lane)-1ull));
        if(slot < TOTAL_K){
            float* out_idx = out;
            float* out_fg  = out + (long)N_IMG*TOTAL_K;
            float* out_cf  = out + (long)2*N_IMG*TOTAL_K;
            out_idx[n*TOTAL_K + slot] = (float)a;
            out_fg [n*TOTAL_K + slot] = (cls==1) ? 1.0f : 0.0f;
            float4 aa = ((const float4*)anchors)[a];
            float4 gg = ((const float4*)gt)[n*M_GT + (mv & 31)];
            float cf[4]; coeff_fn(aa, gg, cf);
            for(int k=0;k<4;++k) out_cf[((long)n*TOTAL_K + slot)*4 + k] = cf[k];
        }
    }
}

extern "C" void kernel_launch(void* const* d_in, const int* in_sizes, int n_in,
                              void* d_out, int out_size, void* d_ws, size_t ws_size,
                              hipStream_t stream){
    const float* anchors = (const float*)d_in[0];  // [36864,4]
    const float* gt      = (const float*)d_in[1];  // [32,32,4]
    const float* dl      = (const float*)d_in[2];  // [32,36864,4]
    const float* rs      = (const float*)d_in[3];  // [32,36864]
    float* out = (float*)d_out;                    // idx[32,256] | fg[32,256] | coeff[32,256,4]
    char* ws = (char*)d_ws;
    size_t off = 0;
    int*      meta    = (int*)(ws + off);      off += (size_t)N_IMG*A_TOT*4;      // 4,718,592
    unsigned* pgm     = (unsigned*)(ws + off); off += 4096;                        // 32*32*4
    int*      hist    = (int*)(ws + off);      off += (size_t)N_IMG*2048*4;       // 262,144
    int*      candcnt = (int*)(ws + off);      off += 256;                         // 32*2*4
    int*      q       = (int*)(ws + off);      off += 512;                         // 32*4*4
    float*    cand_r  = (float*)(ws + off);    off += (size_t)N_IMG*2*CAP*4;      // 131,072
    int*      cand_a  = (int*)(ws + off);      off += (size_t)N_IMG*2*CAP*4;      // 131,072
    int*      chunk_c = (int*)(ws + off);      off += (size_t)N_IMG*NCHUNK*4;     // 18,432
    int*      cbase   = (int*)(ws + off);      off += (size_t)N_IMG*NCHUNK*4;     // 18,432

    hipLaunchKernelGGL(k_init,     dim3(261),          dim3(256), 0, stream, (int*)pgm); // zeros pgm|hist|candcnt (contiguous)
    hipLaunchKernelGGL(k_iou,      dim3(N_IMG*NCHUNK), dim3(256), 0, stream, anchors, gt, dl, pgm);
    hipLaunchKernelGGL(k_label,    dim3(N_IMG*NCHUNK), dim3(256), 0, stream, anchors, gt, dl, rs, meta, pgm, hist);
    hipLaunchKernelGGL(k_quota,    dim3(N_IMG),        dim3(256), 0, stream, hist, q);
    hipLaunchKernelGGL(k_bound,    dim3(N_IMG*NCHUNK), dim3(256), 0, stream, meta, rs, q, chunk_c, candcnt, cand_r, cand_a);
    hipLaunchKernelGGL(k_rankscan, dim3(N_IMG),        dim3(256), 0, stream, anchors, gt, meta, q, candcnt, cand_r, cand_a, chunk_c, cbase, out);
    hipLaunchKernelGGL(k_out,      dim3(N_IMG*NCHUNK), dim3(256), 0, stream, anchors, gt, meta, q, cbase, out);
}

// Round 4
// 171.498 us; speedup vs baseline: 4.9883x; 1.0026x over previous
//
#include <hip/hip_runtime.h>
#include <math.h>

#define A_TOT  36864
#define N_IMG  32
#define M_GT   32
#define TOTAL_K 256
#define MAX_FG_K 128
#define NCHUNK 144          // A_TOT / 256
#define KEEPB  (1<<17)
#define CAP    512
#define RAW_NEG1 ((int)0xBF800000u)   // __float_as_int(-1.0f)
#define RAW_P07  ((int)0x3F333333u)   // __float_as_int(0.7f)
#define RAW_P03  ((int)0x3E99999Au)   // __float_as_int(0.3f)
// IoU values live in {-1.0} ∪ [0,1]; on that domain signed-int compare of the
// raw float bits == float compare (no -0.0, no NaN on the valid path), so all
// max/threshold/equality logic runs on raw bits with zero transform cost.

__device__ __forceinline__ int bin_of(float r){
    int b = (int)(r * 1024.0f);
    return b > 1023 ? 1023 : (b < 0 ? 0 : b);
}

// ---------- inline helpers; contract(off) => pure IEEE fp32, bit-identical in
// ---------- every kernel they are inlined into (no fma fusion / reassociation)
struct Pred { float x1,y1,x2,y2,area; int valid; };

__device__ __forceinline__ Pred mk_pred(float4 a, float4 d){
#pragma clang fp contract(off)
    Pred p;
    float w  = a.z - a.x + 1.0f;
    float h  = a.w - a.y + 1.0f;
    float cx = a.x + 0.5f*w;
    float cy = a.y + 0.5f*h;
    float pcx = d.x*w + cx;
    float pcy = d.y*h + cy;
    float pw = (float)exp((double)d.z) * w;
    float ph = (float)exp((double)d.w) * h;
    p.x1 = pcx - 0.5f*pw;
    p.y1 = pcy - 0.5f*ph;
    p.x2 = pcx + 0.5f*pw;
    p.y2 = pcy + 0.5f*ph;
    p.valid = (p.x1 >= 0.0f) && (p.y1 >= 0.0f) && (p.x2 < 1024.0f) && (p.y2 < 1024.0f);
    p.area  = (p.x2 - p.x1 + 1.0f) * (p.y2 - p.y1 + 1.0f);
    return p;
}

__device__ __forceinline__ float gt_area(float4 g){
#pragma clang fp contract(off)
    return (g.z - g.x + 1.0f) * (g.w - g.y + 1.0f);
}

__device__ __forceinline__ float iou_val(const Pred& p, float gx1, float gy1,
                                         float gx2, float gy2, float ga){
#pragma clang fp contract(off)
    float iw = fminf(p.x2,gx2) - fmaxf(p.x1,gx1) + 1.0f; iw = iw < 0.0f ? 0.0f : iw;
    float ih = fminf(p.y2,gy2) - fmaxf(p.y1,gy1) + 1.0f; ih = ih < 0.0f ? 0.0f : ih;
    float inter = iw * ih;
    float uni = (p.area + ga) - inter;
    float v = inter / uni;
    return p.valid ? v : -1.0f;
}

__device__ __forceinline__ void coeff_fn(float4 a, float4 g, float cf[4]){
#pragma clang fp contract(off)
    float aw = a.z - a.x + 1.0f, ah = a.w - a.y + 1.0f;
    float acx = a.x + 0.5f*aw,  acy = a.y + 0.5f*ah;
    float gw = g.z - g.x + 1.0f, gh = g.w - g.y + 1.0f;
    float gcx = g.x + 0.5f*gw,  gcy = g.y + 0.5f*gh;
    cf[0] = (gcx - acx) / aw;
    cf[1] = (gcy - acy) / ah;
    cf[2] = (float)log((double)(gw / aw));
    cf[3] = (float)log((double)(gh / ah));
}

// ---------- K0: zero [pgm | hist | candcnt] (contiguous, 66624 ints) ----------
// pgm zero-init == +0.0f raw; correct because global max over any valid anchor
// is >= 0.0, and the all-invalid case gives bmax==raw(-1) != 0 -> no abox.
__global__ void k_init(int* base){
    int i = blockIdx.x*256 + threadIdx.x;
    if(i < 66624) base[i] = 0;
}

// ---------- K1: single heavy pass: IoU row in regs, block max, argmax, achmask ----------
__global__ void k_main(const float* __restrict__ anchors, const float* __restrict__ gt,
                       const float* __restrict__ dl, const float* __restrict__ rscore,
                       int* __restrict__ pgm, int* __restrict__ bmax,
                       unsigned* __restrict__ achm, int* __restrict__ meta){
    int blk = blockIdx.x;
    int n = blk / NCHUNK, ch = blk % NCHUNK;
    int tid = threadIdx.x;
    int a = ch*256 + tid;
    __shared__ float4 sgt[M_GT];
    __shared__ float  sga[M_GT];
    __shared__ int    sbm[M_GT];
    if(tid < M_GT){
        float4 g = ((const float4*)gt)[n*M_GT + tid];
        sgt[tid] = g;
        sga[tid] = gt_area(g);
        sbm[tid] = RAW_NEG1;
    }
    __syncthreads();
    float4 anc = ((const float4*)anchors)[a];
    float4 d   = ((const float4*)dl)[(long)n*A_TOT + a];
    Pred p = mk_pred(anc, d);
    int e[M_GT];
    int beste = (int)0x80000000u;    // INT_MIN < raw(-1.0)
    int bid = 0;
    int mm0 = tid & 31;
    #pragma unroll
    for(int j=0;j<M_GT;++j){
        int m = (mm0 + j) & 31;      // stagger: 2-way same-address LDS atomic (free)
        float4 g = sgt[m];
        float v = iou_val(p, g.x, g.y, g.z, g.w, sga[m]);
        int vi = __float_as_int(v);
        e[j] = vi;
        atomicMax(&sbm[m], vi);
        // rotated visit order => explicit (v desc, m asc) tie-break == first argmax
        if(vi > beste || (vi == beste && m < bid)){ beste = vi; bid = m; }
    }
    __syncthreads();
    unsigned ach = 0u;
    if(p.valid){
        #pragma unroll
        for(int j=0;j<M_GT;++j){
            int m = (mm0 + j) & 31;
            if(e[j] == sbm[m]) ach |= (1u << m);
        }
    }
    long ia = (long)n*A_TOT + a;
    achm[ia] = ach;
    int bin = bin_of(rscore[ia]);
    int thrfg = (beste >= RAW_P07) ? 1 : 0;
    int lt03  = (beste <  RAW_P03) ? 1 : 0;
    // interim meta: bid[0:4] | thrfg<<5 | lt03<<6 | valid<<7 | bin<<8
    meta[ia] = bid | (thrfg<<5) | (lt03<<6) | (p.valid ? 128 : 0) | (bin<<8);
    if(tid < M_GT){
        bmax[blk*M_GT + tid] = sbm[tid];
        atomicMax(&pgm[n*M_GT + tid], sbm[tid]);
    }
}

// ---------- K2: resolve abox via (achmask & gmask), finalize labels, histogram ----------
__global__ void k_post(const int* __restrict__ bmax, const int* __restrict__ pgm,
                       const unsigned* __restrict__ achm, int* __restrict__ meta,
                       int* __restrict__ hist){
    int blk = blockIdx.x;
    int n = blk / NCHUNK, ch = blk % NCHUNK;
    int tid = threadIdx.x;
    __shared__ unsigned s_gmask;
    bool eq = (tid < M_GT) && (bmax[blk*M_GT + tid] == pgm[n*M_GT + tid]);
    unsigned long long b = __ballot(eq);          // wave 0 lanes 0..31 hold the mask
    if(tid == 0) s_gmask = (unsigned)(b & 0xFFFFFFFFull);
    __syncthreads();
    unsigned gmask = s_gmask;
    long ia = (long)n*A_TOT + ch*256 + tid;
    int mv0 = meta[ia];
    unsigned ach = achm[ia];
    bool abox = (ach & gmask) != 0u;              // ach already 0 for invalid anchors
    bool fg = abox || ((mv0 >> 5) & 1);
    bool bg = ((mv0 >> 7) & 1) && ((mv0 >> 6) & 1) && !fg;
    int bin = (mv0 >> 8) & 1023;
    // final meta: bid[0:4] | fg<<5 | bg<<6 | bin<<7   (KEEPB bit 17 free)
    meta[ia] = (mv0 & 31) | (fg?32:0) | (bg?64:0) | (bin<<7);
    if(fg || bg) atomicAdd(&hist[(n*2 + (fg?0:1))*1024 + bin], 1);
}

// ---------- K3: per-image quotas: boundary bin + take per class ----------
__global__ void k_quota(const int* __restrict__ hist, int* __restrict__ q){
    int n = blockIdx.x, tid = threadIdx.x;
    __shared__ int sh[2048];
    __shared__ int sscan[256];
    __shared__ int s_b[2], s_t[2], s_fgK;
    for(int i=tid;i<2048;i+=256) sh[i] = hist[n*2048 + i];
    __syncthreads();
    for(int phase=0; phase<2; ++phase){
        int b0 = 1023 - 4*tid;                              // group bins b0..b0-3 (desc)
        int4 h4 = *(const int4*)&sh[phase*1024 + b0 - 3];   // {b0-3,b0-2,b0-1,b0}
        int part = h4.x + h4.y + h4.z + h4.w;
        sscan[tid] = part;
        __syncthreads();
        for(int off=1; off<256; off<<=1){
            int add = (tid>=off) ? sscan[tid-off] : 0;
            __syncthreads();
            sscan[tid] += add;
            __syncthreads();
        }
        int total = sscan[255];
        if(tid==0){
            s_b[phase] = -1; s_t[phase] = 0;
            if(phase==0) s_fgK = (total < MAX_FG_K) ? total : MAX_FG_K;
        }
        __syncthreads();
        int quota = (phase==0) ? MAX_FG_K : (TOTAL_K - s_fgK);
        if(total > quota){
            int pre = sscan[tid] - part;       // count in bins strictly above my group
            int cum = pre;
            int hs[4] = {h4.w, h4.z, h4.y, h4.x};   // descending bin order
            for(int j=0;j<4;++j){
                int hh = hs[j];
                if(cum < quota && cum + hh >= quota){ s_b[phase] = b0 - j; s_t[phase] = quota - cum; }
                cum += hh;
            }
        }
        __syncthreads();
    }
    if(tid==0){
        q[n*4+0]=s_b[0]; q[n*4+1]=s_t[0]; q[n*4+2]=s_b[1]; q[n*4+3]=s_t[1];
    }
}

// ---------- K4: chunk-parallel sure-keep counts + boundary candidate collection ----------
__global__ void k_bound(const int* __restrict__ meta, const float* __restrict__ rscore,
                        const int* __restrict__ q, int* __restrict__ chunk_cnt,
                        int* __restrict__ candcnt, float* __restrict__ cand_r,
                        int* __restrict__ cand_a){
    int blk = blockIdx.x;
    int n = blk / NCHUNK, ch = blk % NCHUNK;
    int tid = threadIdx.x;
    int wave = tid >> 6, lane = tid & 63;
    int a = ch*256 + tid;
    int4 qq = *(const int4*)&q[n*4];            // bsel0, take0, bsel1, take1
    long ia = (long)n*A_TOT + a;
    int mv = meta[ia];
    int cls = (mv >> 5) & 3;                    // 1=fg, 2=bg
    int kept = 0;
    if(cls){
        int c = (cls==1) ? 0 : 1;
        int bsel = c ? qq.z : qq.x;
        int bin = (mv >> 7) & 1023;
        if(bin > bsel) kept = 1;                // keepAll encoded as bsel=-1
        else if(bin == bsel){
            int pos = atomicAdd(&candcnt[n*2+c], 1);
            if(pos < CAP){
                int ci = (n*2+c)*CAP + pos;
                cand_r[ci] = rscore[ia];
                cand_a[ci] = a;
            }
        }
    }
    __shared__ int wc[4];
    unsigned long long mask = __ballot(kept);
    if(lane==0) wc[wave] = __popcll(mask);
    __syncthreads();
    if(tid==0) chunk_cnt[n*NCHUNK + ch] = wc[0]+wc[1]+wc[2]+wc[3];
}

// ---------- K5: rank boundary candidates, chunk-base scan, default outputs ----------
__global__ void k_rankscan(const float* __restrict__ anchors, const float* __restrict__ gt,
                           int* __restrict__ meta, const int* __restrict__ q,
                           const int* __restrict__ candcnt,
                           const float* __restrict__ cand_r, const int* __restrict__ cand_a,
                           const int* __restrict__ chunk_cnt, int* __restrict__ cbase,
                           float* __restrict__ out){
    int n = blockIdx.x, tid = threadIdx.x;
    __shared__ int s_chunk[NCHUNK];
    __shared__ int sscan[256];
    __shared__ int s_k0b;                        // anchor0 boundary-kept-as-fg flag
    if(tid < NCHUNK) s_chunk[tid] = chunk_cnt[n*NCHUNK + tid];
    if(tid==0) s_k0b = 0;
    int4 qq = *(const int4*)&q[n*4];
    __syncthreads();
    for(int c=0;c<2;++c){
        int cc = candcnt[n*2+c]; if(cc > CAP) cc = CAP;
        int take = c ? qq.w : qq.y;
        for(int i=tid; i<cc; i+=256){
            int ci = (n*2+c)*CAP + i;
            float ri = cand_r[ci]; int ai = cand_a[ci]; int rank = 0;
            for(int j=0;j<cc;++j){
                float rj = cand_r[(n*2+c)*CAP + j];
                if(rj > ri || (rj == ri && cand_a[(n*2+c)*CAP + j] < ai)) rank++;
            }
            if(rank < take){
                meta[(long)n*A_TOT + ai] |= KEEPB;
                atomicAdd(&s_chunk[ai >> 8], 1);
                if(ai == 0 && c == 0) s_k0b = 1;
            }
        }
    }
    __syncthreads();
    int v = (tid < NCHUNK) ? s_chunk[tid] : 0;
    sscan[tid] = v;
    __syncthreads();
    for(int off=1; off<256; off<<=1){
        int add = (tid>=off) ? sscan[tid-off] : 0;
        __syncthreads();
        sscan[tid] += add;
        __syncthreads();
    }
    if(tid < NCHUNK) cbase[n*NCHUNK + tid] = sscan[tid] - v;
    // defaults: padding slots behave like anchor 0 (reference zero-init scatter).
    int m0 = meta[(long)n*A_TOT];
    int cls0 = (m0 >> 5) & 3, bin0 = (m0 >> 7) & 1023;
    float fgdef = ((cls0 == 1) && (bin0 > qq.x || s_k0b)) ? 1.0f : 0.0f;
    float4 a0 = ((const float4*)anchors)[0];
    float4 g0 = ((const float4*)gt)[n*M_GT + (m0 & 31)];
    float cf0[4]; coeff_fn(a0, g0, cf0);
    float* out_idx = out;
    float* out_fg  = out + (long)N_IMG*TOTAL_K;
    float* out_cf  = out + (long)2*N_IMG*TOTAL_K;
    out_idx[n*TOTAL_K + tid] = 0.0f;
    out_fg [n*TOTAL_K + tid] = fgdef;
    for(int k=0;k<4;++k) out_cf[((long)n*TOTAL_K + tid)*4 + k] = cf0[k];
}

// ---------- K6: chunk-parallel compaction + emit ----------
__global__ void k_out(const float* __restrict__ anchors, const float* __restrict__ gt,
                      const int* __restrict__ meta, const int* __restrict__ q,
                      const int* __restrict__ cbase, float* __restrict__ out){
    int blk = blockIdx.x;
    int n = blk / NCHUNK, ch = blk % NCHUNK;
    int tid = threadIdx.x;
    int wave = tid >> 6, lane = tid & 63;
    int a = ch*256 + tid;
    int4 qq = *(const int4*)&q[n*4];
    int mv = meta[(long)n*A_TOT + a];
    int cls = (mv >> 5) & 3;
    int kept = 0;
    if(cls){
        int c = (cls==1) ? 0 : 1;
        int bsel = c ? qq.z : qq.x;
        int bin = (mv >> 7) & 1023;
        kept = (bin > bsel) || ((mv & KEEPB) != 0);
    }
    __shared__ int wc[4];
    unsigned long long mask = __ballot(kept);
    if(lane==0) wc[wave] = __popcll(mask);
    __syncthreads();
    if(kept){
        int base = cbase[n*NCHUNK + ch];
        for(int w=0; w<wave; ++w) base += wc[w];
        int slot = base + __popcll(mask & ((1ull<<lane)-1ull));
        if(slot < TOTAL_K){
            float* out_idx = out;
            float* out_fg  = out + (long)N_IMG*TOTAL_K;
            float* out_cf  = out + (long)2*N_IMG*TOTAL_K;
            out_idx[n*TOTAL_K + slot] = (float)a;
            out_fg [n*TOTAL_K + slot] = (cls==1) ? 1.0f : 0.0f;
            float4 aa = ((const float4*)anchors)[a];
            float4 gg = ((const float4*)gt)[n*M_GT + (mv & 31)];
            float cf[4]; coeff_fn(aa, gg, cf);
            for(int k=0;k<4;++k) out_cf[((long)n*TOTAL_K + slot)*4 + k] = cf[k];
        }
    }
}

extern "C" void kernel_launch(void* const* d_in, const int* in_sizes, int n_in,
                              void* d_out, int out_size, void* d_ws, size_t ws_size,
                              hipStream_t stream){
    const float* anchors = (const float*)d_in[0];  // [36864,4]
    const float* gt      = (const float*)d_in[1];  // [32,32,4]
    const float* dl      = (const float*)d_in[2];  // [32,36864,4]
    const float* rs      = (const float*)d_in[3];  // [32,36864]
    float* out = (float*)d_out;                    // idx[32,256] | fg[32,256] | coeff[32,256,4]
    char* ws = (char*)d_ws;
    size_t off = 0;
    int*      meta    = (int*)(ws + off);      off += (size_t)N_IMG*A_TOT*4;      // 4,718,592
    int*      pgm     = (int*)(ws + off);      off += 4096;                        // 32*32*4
    int*      hist    = (int*)(ws + off);      off += (size_t)N_IMG*2048*4;       // 262,144
    int*      candcnt = (int*)(ws + off);      off += 256;                         // 32*2*4
    int*      q       = (int*)(ws + off);      off += 512;
    float*    cand_r  = (float*)(ws + off);    off += (size_t)N_IMG*2*CAP*4;
    int*      cand_a  = (int*)(ws + off);      off += (size_t)N_IMG*2*CAP*4;
    int*      chunk_c = (int*)(ws + off);      off += (size_t)N_IMG*NCHUNK*4;
    int*      cbase   = (int*)(ws + off);      off += (size_t)N_IMG*NCHUNK*4;
    unsigned* achm    = (unsigned*)(ws + off); off += (size_t)N_IMG*A_TOT*4;      // 4,718,592
    int*      bmax    = (int*)(ws + off);      off += (size_t)N_IMG*NCHUNK*M_GT*4;// 589,824

    hipLaunchKernelGGL(k_init,     dim3(261),          dim3(256), 0, stream, pgm); // zeros pgm|hist|candcnt (contiguous)
    hipLaunchKernelGGL(k_main,     dim3(N_IMG*NCHUNK), dim3(256), 0, stream, anchors, gt, dl, rs, pgm, bmax, achm, meta);
    hipLaunchKernelGGL(k_post,     dim3(N_IMG*NCHUNK), dim3(256), 0, stream, bmax, pgm, achm, meta, hist);
    hipLaunchKernelGGL(k_quota,    dim3(N_IMG),        dim3(256), 0, stream, hist, q);
    hipLaunchKernelGGL(k_bound,    dim3(N_IMG*NCHUNK), dim3(256), 0, stream, meta, rs, q, chunk_c, candcnt, cand_r, cand_a);
    hipLaunchKernelGGL(k_rankscan, dim3(N_IMG),        dim3(256), 0, stream, anchors, gt, meta, q, candcnt, cand_r, cand_a, chunk_c, cbase, out);
    hipLaunchKernelGGL(k_out,      dim3(N_IMG*NCHUNK), dim3(256), 0, stream, anchors, gt, meta, q, cbase, out);
}